// Round 1
// baseline (1114.885 us; speedup 1.0000x reference)
//
#include <hip/hip_runtime.h>

typedef __attribute__((ext_vector_type(4))) float f32x4;
typedef __attribute__((ext_vector_type(8))) short bf16x8;

constexpr int TOK = 8192;   // B*S
constexpr int DD  = 1024;   // D
constexpr int HH  = 2048;   // H
constexpr int NE  = 8;      // experts

// ---- workspace layout (bytes) ----
// 0       : topk_idx   int[16384]
// 65536   : topk_prob  f32[16384]
// 131072  : counts     int[8]
// 131104  : cursor     int[8]
// 131136  : offsets    int[9]
// 131200  : token_list int[16384]
// 196736  : prob_list  f32[16384]
// 262272  : act        bf16[16384][2048]   (67.1 MB)
// total ~67.4 MB

__device__ __forceinline__ unsigned short f2bf(float f) {
    union { float f; unsigned u; } v; v.f = f;
    unsigned r = v.u + 0x7fffu + ((v.u >> 16) & 1u);   // RNE
    return (unsigned short)(r >> 16);
}

// ---------------- router: logits, top-2, renormalized probs ----------------
__global__ __launch_bounds__(256) void k_router(
    const float* __restrict__ x, const float* __restrict__ rw,
    int* __restrict__ topk_idx, float* __restrict__ topk_prob,
    int* __restrict__ counts)
{
    int wave = threadIdx.x >> 6;
    int lane = threadIdx.x & 63;
    int t = blockIdx.x * 4 + wave;

    const float4* xr = (const float4*)(x + (size_t)t * DD);
    float4 xv[4];
#pragma unroll
    for (int i = 0; i < 4; i++) xv[i] = xr[lane + 64 * i];

    float acc[NE];
#pragma unroll
    for (int e = 0; e < NE; e++) {
        const float4* wr = (const float4*)(rw + (size_t)e * DD);
        float s = 0.f;
#pragma unroll
        for (int i = 0; i < 4; i++) {
            float4 w = wr[lane + 64 * i];
            s += xv[i].x * w.x + xv[i].y * w.y + xv[i].z * w.z + xv[i].w * w.w;
        }
        acc[e] = s;
    }
#pragma unroll
    for (int e = 0; e < NE; e++) {
        float s = acc[e];
        for (int m = 32; m >= 1; m >>= 1) s += __shfl_xor(s, m);
        acc[e] = s;
    }
    if (lane == 0) {
        int b0 = 0; float l0 = acc[0];
#pragma unroll
        for (int e = 1; e < NE; e++) if (acc[e] > l0) { l0 = acc[e]; b0 = e; }
        int b1 = -1; float l1 = -3.0e38f;
#pragma unroll
        for (int e = 0; e < NE; e++) if (e != b0 && acc[e] > l1) { l1 = acc[e]; b1 = e; }
        // renormalized top-2 softmax probs: full-softmax denom cancels
        float p0 = 1.f / (1.f + __expf(l1 - l0));
        float p1 = 1.f - p0;
        topk_idx[t * 2 + 0] = b0;  topk_idx[t * 2 + 1] = b1;
        topk_prob[t * 2 + 0] = p0; topk_prob[t * 2 + 1] = p1;
        atomicAdd(&counts[b0], 1);
        atomicAdd(&counts[b1], 1);
    }
}

__global__ void k_scan(const int* __restrict__ counts, int* __restrict__ offsets) {
    if (threadIdx.x == 0) {
        int s = 0;
        for (int e = 0; e < NE; e++) { offsets[e] = s; s += counts[e]; }
        offsets[NE] = s;
    }
}

__global__ __launch_bounds__(256) void k_scatter(
    const int* __restrict__ topk_idx, const float* __restrict__ topk_prob,
    const int* __restrict__ offsets, int* __restrict__ cursor,
    int* __restrict__ token_list, float* __restrict__ prob_list)
{
    int t = blockIdx.x * 256 + threadIdx.x;
#pragma unroll
    for (int k = 0; k < 2; k++) {
        int e = topk_idx[t * 2 + k];
        float p = topk_prob[t * 2 + k];
        int pos = atomicAdd(&cursor[e], 1);
        token_list[offsets[e] + pos] = t;
        prob_list[offsets[e] + pos] = p;
    }
}

// ---------------- fused gate/up GEMM + silu ----------------
// act[row, h] = silu(x_row . gate_w[e][h]) * (x_row . up_w[e][h]),  bf16 out
// Tile: BM=128 x BN=64, BK=64. 4 waves in 2x2, each 64x32 via 4x2 16x16x32 MFMA.
constexpr int BM = 128, BN = 64, BK = 64;

__global__ __launch_bounds__(256) void k_gateup(
    const float* __restrict__ x,
    const float* __restrict__ gate_w,
    const float* __restrict__ up_w,
    const int* __restrict__ offsets,
    const int* __restrict__ token_list,
    unsigned short* __restrict__ act)
{
    const int e = blockIdx.z;
    const int off = offsets[e];
    const int n_e = offsets[e + 1] - off;
    const int m0 = blockIdx.y * BM;
    if (m0 >= n_e) return;
    const int n0 = blockIdx.x * BN;

    __shared__ unsigned short lds_a[BM * BK];
    __shared__ unsigned short lds_g[BN * BK];
    __shared__ unsigned short lds_u[BN * BK];

    const int tid = threadIdx.x;
    const int lane = tid & 63;
    const int wid = tid >> 6;
    const int wm = wid >> 1, wn = wid & 1;

    const float* gw = gate_w + (size_t)e * HH * DD;
    const float* uw = up_w + (size_t)e * HH * DD;

    // hoist gathered A-row pointers (8 rows per thread)
    const float* arow[8];
    bool arow_ok[8];
#pragma unroll
    for (int p = 0; p < 8; p++) {
        int rg = m0 + (tid >> 4) + p * 16;
        arow_ok[p] = (rg < n_e);
        int tok = arow_ok[p] ? token_list[off + rg] : 0;
        arow[p] = x + (size_t)tok * DD;
    }

    f32x4 accg[4][2] = {};
    f32x4 accu[4][2] = {};

    for (int k0 = 0; k0 < DD; k0 += BK) {
        __syncthreads();
        // --- stage A (gathered tokens), f32 -> bf16, XOR-swizzled ---
#pragma unroll
        for (int p = 0; p < 8; p++) {
            int row = (tid >> 4) + p * 16;
            int col4 = (tid & 15) * 4;
            ushort4 u4 = make_ushort4(0, 0, 0, 0);
            if (arow_ok[p]) {
                const float4 v = *(const float4*)(arow[p] + k0 + col4);
                u4 = make_ushort4(f2bf(v.x), f2bf(v.y), f2bf(v.z), f2bf(v.w));
            }
            int sw = col4 ^ ((row & 7) << 3);
            *(ushort4*)&lds_a[row * BK + sw] = u4;
        }
        // --- stage gate/up weight tiles ---
#pragma unroll
        for (int p = 0; p < 4; p++) {
            int row = (tid >> 4) + p * 16;
            int col4 = (tid & 15) * 4;
            int sw = col4 ^ ((row & 7) << 3);
            size_t gidx = (size_t)(n0 + row) * DD + k0 + col4;
            {
                const float4 v = *(const float4*)(gw + gidx);
                *(ushort4*)&lds_g[row * BK + sw] =
                    make_ushort4(f2bf(v.x), f2bf(v.y), f2bf(v.z), f2bf(v.w));
            }
            {
                const float4 v = *(const float4*)(uw + gidx);
                *(ushort4*)&lds_u[row * BK + sw] =
                    make_ushort4(f2bf(v.x), f2bf(v.y), f2bf(v.z), f2bf(v.w));
            }
        }
        __syncthreads();
#pragma unroll
        for (int kk = 0; kk < BK; kk += 32) {
            bf16x8 af[4], gf[2], uf[2];
            int kcol = kk + (lane >> 4) * 8;
#pragma unroll
            for (int mi = 0; mi < 4; mi++) {
                int row = wm * 64 + mi * 16 + (lane & 15);
                int sw = kcol ^ ((row & 7) << 3);
                af[mi] = *(const bf16x8*)&lds_a[row * BK + sw];
            }
#pragma unroll
            for (int ni = 0; ni < 2; ni++) {
                int row = wn * 32 + ni * 16 + (lane & 15);
                int sw = kcol ^ ((row & 7) << 3);
                gf[ni] = *(const bf16x8*)&lds_g[row * BK + sw];
                uf[ni] = *(const bf16x8*)&lds_u[row * BK + sw];
            }
#pragma unroll
            for (int mi = 0; mi < 4; mi++)
#pragma unroll
                for (int ni = 0; ni < 2; ni++) {
                    accg[mi][ni] = __builtin_amdgcn_mfma_f32_16x16x32_bf16(af[mi], gf[ni], accg[mi][ni], 0, 0, 0);
                    accu[mi][ni] = __builtin_amdgcn_mfma_f32_16x16x32_bf16(af[mi], uf[ni], accu[mi][ni], 0, 0, 0);
                }
        }
    }
    // epilogue: silu(g)*u -> act  (C/D layout: col=lane&15, row=(lane>>4)*4+r)
#pragma unroll
    for (int mi = 0; mi < 4; mi++) {
#pragma unroll
        for (int r = 0; r < 4; r++) {
            int row = wm * 64 + mi * 16 + (lane >> 4) * 4 + r;
            int rg = m0 + row;
            if (rg >= n_e) continue;
            size_t rowbase = (size_t)(off + rg) * HH + n0 + wn * 32;
#pragma unroll
            for (int ni = 0; ni < 2; ni++) {
                float g = accg[mi][ni][r];
                float u = accu[mi][ni][r];
                float s = g / (1.f + __expf(-g)) * u;
                act[rowbase + ni * 16 + (lane & 15)] = f2bf(s);
            }
        }
    }
}

// ---------------- down GEMM + weighted scatter-add ----------------
__global__ __launch_bounds__(256) void k_down(
    const unsigned short* __restrict__ act,
    const float* __restrict__ down_w,
    const int* __restrict__ offsets,
    const int* __restrict__ token_list,
    const float* __restrict__ prob_list,
    float* __restrict__ out)
{
    const int e = blockIdx.z;
    const int off = offsets[e];
    const int n_e = offsets[e + 1] - off;
    const int m0 = blockIdx.y * BM;
    if (m0 >= n_e) return;
    const int n0 = blockIdx.x * BN;   // D cols

    __shared__ unsigned short lds_a[BM * BK];
    __shared__ unsigned short lds_b[BN * BK];

    const int tid = threadIdx.x;
    const int lane = tid & 63;
    const int wid = tid >> 6;
    const int wm = wid >> 1, wn = wid & 1;

    const float* dw = down_w + (size_t)e * DD * HH;

    f32x4 acc[4][2] = {};

    for (int k0 = 0; k0 < HH; k0 += BK) {
        __syncthreads();
        // --- stage A from act (already bf16): 16B loads ---
#pragma unroll
        for (int p = 0; p < 4; p++) {
            int row = (tid >> 3) + p * 32;
            int col8 = (tid & 7) * 8;
            int rg = m0 + row;
            uint4 v = make_uint4(0, 0, 0, 0);
            if (rg < n_e)
                v = *(const uint4*)(act + (size_t)(off + rg) * HH + k0 + col8);
            int sw = col8 ^ ((row & 7) << 3);
            *(uint4*)&lds_a[row * BK + sw] = v;
        }
        // --- stage B from down_w, f32 -> bf16 ---
#pragma unroll
        for (int p = 0; p < 4; p++) {
            int row = (tid >> 4) + p * 16;
            int col4 = (tid & 15) * 4;
            const float4 v = *(const float4*)(dw + (size_t)(n0 + row) * HH + k0 + col4);
            int sw = col4 ^ ((row & 7) << 3);
            *(ushort4*)&lds_b[row * BK + sw] =
                make_ushort4(f2bf(v.x), f2bf(v.y), f2bf(v.z), f2bf(v.w));
        }
        __syncthreads();
#pragma unroll
        for (int kk = 0; kk < BK; kk += 32) {
            bf16x8 af[4], bfrag[2];
            int kcol = kk + (lane >> 4) * 8;
#pragma unroll
            for (int mi = 0; mi < 4; mi++) {
                int row = wm * 64 + mi * 16 + (lane & 15);
                int sw = kcol ^ ((row & 7) << 3);
                af[mi] = *(const bf16x8*)&lds_a[row * BK + sw];
            }
#pragma unroll
            for (int ni = 0; ni < 2; ni++) {
                int row = wn * 32 + ni * 16 + (lane & 15);
                int sw = kcol ^ ((row & 7) << 3);
                bfrag[ni] = *(const bf16x8*)&lds_b[row * BK + sw];
            }
#pragma unroll
            for (int mi = 0; mi < 4; mi++)
#pragma unroll
                for (int ni = 0; ni < 2; ni++)
                    acc[mi][ni] = __builtin_amdgcn_mfma_f32_16x16x32_bf16(af[mi], bfrag[ni], acc[mi][ni], 0, 0, 0);
        }
    }
    // epilogue: out[token] += prob * result  (atomic f32, 2 adds/token total)
#pragma unroll
    for (int mi = 0; mi < 4; mi++) {
#pragma unroll
        for (int r = 0; r < 4; r++) {
            int row = wm * 64 + mi * 16 + (lane >> 4) * 4 + r;
            int rg = m0 + row;
            if (rg >= n_e) continue;
            int tok = token_list[off + rg];
            float p = prob_list[off + rg];
            size_t obase = (size_t)tok * DD + n0 + wn * 32;
#pragma unroll
            for (int ni = 0; ni < 2; ni++)
                atomicAdd(&out[obase + ni * 16 + (lane & 15)], acc[mi][ni][r] * p);
        }
    }
}

extern "C" void kernel_launch(void* const* d_in, const int* in_sizes, int n_in,
                              void* d_out, int out_size, void* d_ws, size_t ws_size,
                              hipStream_t stream) {
    const float* x  = (const float*)d_in[0];
    const float* rw = (const float*)d_in[1];
    const float* gw = (const float*)d_in[2];
    const float* uw = (const float*)d_in[3];
    const float* dw = (const float*)d_in[4];
    float* out = (float*)d_out;

    char* ws = (char*)d_ws;
    int*   topk_idx   = (int*)(ws + 0);
    float* topk_prob  = (float*)(ws + 65536);
    int*   counts     = (int*)(ws + 131072);
    int*   cursor     = (int*)(ws + 131104);
    int*   offsets    = (int*)(ws + 131136);
    int*   token_list = (int*)(ws + 131200);
    float* prob_list  = (float*)(ws + 196736);
    unsigned short* act = (unsigned short*)(ws + 262272);

    hipMemsetAsync(d_out, 0, (size_t)out_size * sizeof(float), stream);
    hipMemsetAsync(ws + 131072, 0, 64, stream);   // counts + cursor

    k_router<<<TOK / 4, 256, 0, stream>>>(x, rw, topk_idx, topk_prob, counts);
    k_scan<<<1, 64, 0, stream>>>(counts, offsets);
    k_scatter<<<TOK / 256, 256, 0, stream>>>(topk_idx, topk_prob, offsets, cursor,
                                             token_list, prob_list);
    k_gateup<<<dim3(HH / BN, TOK / BM, NE), 256, 0, stream>>>(x, gw, uw, offsets,
                                                              token_list, act);
    k_down<<<dim3(DD / BN, TOK / BM, NE), 256, 0, stream>>>(act, dw, offsets,
                                                            token_list, prob_list, out);
}

// Round 2
// 712.263 us; speedup vs baseline: 1.5653x; 1.5653x over previous
//
#include <hip/hip_runtime.h>

typedef __attribute__((ext_vector_type(4))) float f32x4;
typedef __attribute__((ext_vector_type(8))) short bf16x8;

constexpr int TOK = 8192;   // B*S
constexpr int DD  = 1024;   // D
constexpr int HH  = 2048;   // H
constexpr int NE  = 8;      // experts

// ---- workspace layout (bytes) ----
// small section [0, 524288):
//   0      topk_idx   int[16384]
//   65536  topk_prob  f32[16384]
//   131072 counts     int[8]
//   131104 cursor     int[8]
//   131136 offsets    int[9]
//   131264 token_list int[16384]
//   196800 prob_list  f32[16384]
// big path (needs 185,073,664 B):
//   524288            x_bf   bf16[8192*1024]      (16.8 MB)
//   17301504          gw_bf  bf16[8*2048*1024]    (33.6 MB)
//   50855936          uw_bf  bf16[8*2048*1024]    (33.6 MB)
//   84410368          dw_bf  bf16[8*1024*2048]    (33.6 MB)
//   117964800         act    bf16[16384*2048]     (67.1 MB)
// fallback path: act at 524288 (needs 67.7 MB)

__device__ __forceinline__ unsigned short f2bf(float f) {
    union { float f; unsigned u; } v; v.f = f;
    unsigned r = v.u + 0x7fffu + ((v.u >> 16) & 1u);   // RNE
    return (unsigned short)(r >> 16);
}

__device__ __forceinline__ void gl2lds16(const void* g, void* l) {
    __builtin_amdgcn_global_load_lds(
        (const __attribute__((address_space(1))) unsigned int*)g,
        (__attribute__((address_space(3))) unsigned int*)l, 16, 0, 0);
}

// ---------------- router: logits, top-2, renormalized probs ----------------
__global__ __launch_bounds__(256) void k_router(
    const float* __restrict__ x, const float* __restrict__ rw,
    int* __restrict__ topk_idx, float* __restrict__ topk_prob,
    int* __restrict__ counts)
{
    int wave = threadIdx.x >> 6;
    int lane = threadIdx.x & 63;
    int t = blockIdx.x * 4 + wave;

    const float4* xr = (const float4*)(x + (size_t)t * DD);
    float4 xv[4];
#pragma unroll
    for (int i = 0; i < 4; i++) xv[i] = xr[lane + 64 * i];

    float acc[NE];
#pragma unroll
    for (int e = 0; e < NE; e++) {
        const float4* wr = (const float4*)(rw + (size_t)e * DD);
        float s = 0.f;
#pragma unroll
        for (int i = 0; i < 4; i++) {
            float4 w = wr[lane + 64 * i];
            s += xv[i].x * w.x + xv[i].y * w.y + xv[i].z * w.z + xv[i].w * w.w;
        }
        acc[e] = s;
    }
#pragma unroll
    for (int e = 0; e < NE; e++) {
        float s = acc[e];
        for (int m = 32; m >= 1; m >>= 1) s += __shfl_xor(s, m);
        acc[e] = s;
    }
    if (lane == 0) {
        int b0 = 0; float l0 = acc[0];
#pragma unroll
        for (int e = 1; e < NE; e++) if (acc[e] > l0) { l0 = acc[e]; b0 = e; }
        int b1 = -1; float l1 = -3.0e38f;
#pragma unroll
        for (int e = 0; e < NE; e++) if (e != b0 && acc[e] > l1) { l1 = acc[e]; b1 = e; }
        float p0 = 1.f / (1.f + __expf(l1 - l0));
        float p1 = 1.f - p0;
        topk_idx[t * 2 + 0] = b0;  topk_idx[t * 2 + 1] = b1;
        topk_prob[t * 2 + 0] = p0; topk_prob[t * 2 + 1] = p1;
        atomicAdd(&counts[b0], 1);
        atomicAdd(&counts[b1], 1);
    }
}

__global__ void k_scan(const int* __restrict__ counts, int* __restrict__ offsets) {
    if (threadIdx.x == 0) {
        int s = 0;
        for (int e = 0; e < NE; e++) { offsets[e] = s; s += counts[e]; }
        offsets[NE] = s;
    }
}

__global__ __launch_bounds__(256) void k_scatter(
    const int* __restrict__ topk_idx, const float* __restrict__ topk_prob,
    const int* __restrict__ offsets, int* __restrict__ cursor,
    int* __restrict__ token_list, float* __restrict__ prob_list)
{
    int t = blockIdx.x * 256 + threadIdx.x;
#pragma unroll
    for (int k = 0; k < 2; k++) {
        int e = topk_idx[t * 2 + k];
        float p = topk_prob[t * 2 + k];
        int pos = atomicAdd(&cursor[e], 1);
        token_list[offsets[e] + pos] = t;
        prob_list[offsets[e] + pos] = p;
    }
}

// ---------------- f32 -> bf16 bulk convert (8 elems/thread/iter) ----------------
__global__ __launch_bounds__(256) void k_cvt8(
    const float* __restrict__ in, unsigned short* __restrict__ out, int n8)
{
    int i = blockIdx.x * blockDim.x + threadIdx.x;
    int stride = gridDim.x * blockDim.x;
    for (; i < n8; i += stride) {
        const float4* p = (const float4*)(in + (size_t)i * 8);
        float4 a = p[0], b = p[1];
        uint4 v;
        v.x = (unsigned)f2bf(a.x) | ((unsigned)f2bf(a.y) << 16);
        v.y = (unsigned)f2bf(a.z) | ((unsigned)f2bf(a.w) << 16);
        v.z = (unsigned)f2bf(b.x) | ((unsigned)f2bf(b.y) << 16);
        v.w = (unsigned)f2bf(b.z) | ((unsigned)f2bf(b.w) << 16);
        *(uint4*)(out + (size_t)i * 8) = v;
    }
}

// ================ bf16 GEMM path (global_load_lds, swizzled LDS) ================
// gateup: BM=128 x BN=64 (gate and up each), BK=64. 4 waves 2x2, wave = 64x32.
__global__ __launch_bounds__(256) void k_gateup_bf(
    const unsigned short* __restrict__ xb,
    const unsigned short* __restrict__ gwb,
    const unsigned short* __restrict__ uwb,
    const int* __restrict__ offsets,
    const int* __restrict__ token_list,
    unsigned short* __restrict__ act)
{
    const int e = blockIdx.z;
    const int off = offsets[e];
    const int n_e = offsets[e + 1] - off;
    const int m0 = blockIdx.y * 128;
    if (m0 >= n_e) return;
    const int n0 = blockIdx.x * 64;

    __shared__ unsigned short lds_a[128 * 64];
    __shared__ unsigned short lds_g[64 * 64];
    __shared__ unsigned short lds_u[64 * 64];

    const int tid = threadIdx.x, lane = tid & 63, wid = tid >> 6;
    const int wm = wid >> 1, wn = wid & 1;
    const int l8 = lane >> 3;
    const int c16 = (lane & 7) * 16;
    const int colb = c16 ^ (l8 << 4);    // pre-swizzled source column byte

    // A: 16 chunks of 1KB (8 rows each); this wave stages chunks wid*4+i
    const char* srcA[4];
#pragma unroll
    for (int i = 0; i < 4; i++) {
        int c = wid * 4 + i;
        int rg = m0 + c * 8 + l8;
        if (rg > n_e - 1) rg = n_e - 1;
        int tok = token_list[off + rg];
        srcA[i] = (const char*)xb + (size_t)tok * (DD * 2) + colb;
    }
    const char* srcG[2]; const char* srcU[2];
#pragma unroll
    for (int i = 0; i < 2; i++) {
        int c = wid * 2 + i;
        size_t rb = ((size_t)e * HH + n0 + c * 8 + l8) * (DD * 2) + colb;
        srcG[i] = (const char*)gwb + rb;
        srcU[i] = (const char*)uwb + rb;
    }

    f32x4 accg[4][2] = {};
    f32x4 accu[4][2] = {};

    for (int k0 = 0; k0 < DD * 2; k0 += 128) {   // byte step along K
        __syncthreads();
#pragma unroll
        for (int i = 0; i < 4; i++)
            gl2lds16(srcA[i] + k0, &lds_a[(wid * 4 + i) * 512]);
#pragma unroll
        for (int i = 0; i < 2; i++) {
            gl2lds16(srcG[i] + k0, &lds_g[(wid * 2 + i) * 512]);
            gl2lds16(srcU[i] + k0, &lds_u[(wid * 2 + i) * 512]);
        }
        __syncthreads();   // compiler drains vmcnt before barrier
#pragma unroll
        for (int kk = 0; kk < 2; kk++) {
            const int kb = kk * 64 + (lane >> 4) * 16;  // byte col in 128-B row
            bf16x8 af[4], gf[2], uf[2];
#pragma unroll
            for (int mi = 0; mi < 4; mi++) {
                int row = wm * 64 + mi * 16 + (lane & 15);
                af[mi] = *(const bf16x8*)((const char*)lds_a + row * 128 + (kb ^ ((row & 7) << 4)));
            }
#pragma unroll
            for (int nj = 0; nj < 2; nj++) {
                int row = wn * 32 + nj * 16 + (lane & 15);
                int ad = row * 128 + (kb ^ ((row & 7) << 4));
                gf[nj] = *(const bf16x8*)((const char*)lds_g + ad);
                uf[nj] = *(const bf16x8*)((const char*)lds_u + ad);
            }
#pragma unroll
            for (int mi = 0; mi < 4; mi++)
#pragma unroll
                for (int nj = 0; nj < 2; nj++) {
                    accg[mi][nj] = __builtin_amdgcn_mfma_f32_16x16x32_bf16(af[mi], gf[nj], accg[mi][nj], 0, 0, 0);
                    accu[mi][nj] = __builtin_amdgcn_mfma_f32_16x16x32_bf16(af[mi], uf[nj], accu[mi][nj], 0, 0, 0);
                }
        }
    }
    // epilogue: silu(g)*u -> act bf16
#pragma unroll
    for (int mi = 0; mi < 4; mi++) {
#pragma unroll
        for (int r = 0; r < 4; r++) {
            int row = wm * 64 + mi * 16 + (lane >> 4) * 4 + r;
            int rg = m0 + row;
            if (rg >= n_e) continue;
            size_t rowbase = (size_t)(off + rg) * HH + n0 + wn * 32;
#pragma unroll
            for (int nj = 0; nj < 2; nj++) {
                float g = accg[mi][nj][r];
                float u = accu[mi][nj][r];
                float s = g / (1.f + __expf(-g)) * u;
                act[rowbase + nj * 16 + (lane & 15)] = f2bf(s);
            }
        }
    }
}

// down: BM=128 x BN=128, BK=64. 4 waves 2x2, wave = 64x64.
__global__ __launch_bounds__(256) void k_down_bf(
    const unsigned short* __restrict__ act,
    const unsigned short* __restrict__ dwb,
    const int* __restrict__ offsets,
    const int* __restrict__ token_list,
    const float* __restrict__ prob_list,
    float* __restrict__ out)
{
    const int e = blockIdx.z;
    const int off = offsets[e];
    const int n_e = offsets[e + 1] - off;
    const int m0 = blockIdx.y * 128;
    if (m0 >= n_e) return;
    const int n0 = blockIdx.x * 128;

    __shared__ unsigned short lds_a[128 * 64];
    __shared__ unsigned short lds_b[128 * 64];

    const int tid = threadIdx.x, lane = tid & 63, wid = tid >> 6;
    const int wm = wid >> 1, wn = wid & 1;
    const int l8 = lane >> 3;
    const int c16 = (lane & 7) * 16;
    const int colb = c16 ^ (l8 << 4);

    const char* srcA[4];
    const char* srcB[4];
#pragma unroll
    for (int i = 0; i < 4; i++) {
        int c = wid * 4 + i;
        int rg = m0 + c * 8 + l8;
        if (rg > n_e - 1) rg = n_e - 1;
        srcA[i] = (const char*)act + (size_t)(off + rg) * (HH * 2) + colb;
        srcB[i] = (const char*)dwb + ((size_t)e * DD + n0 + c * 8 + l8) * (HH * 2) + colb;
    }

    f32x4 acc[4][4] = {};

    for (int k0 = 0; k0 < HH * 2; k0 += 128) {
        __syncthreads();
#pragma unroll
        for (int i = 0; i < 4; i++) {
            gl2lds16(srcA[i] + k0, &lds_a[(wid * 4 + i) * 512]);
            gl2lds16(srcB[i] + k0, &lds_b[(wid * 4 + i) * 512]);
        }
        __syncthreads();
#pragma unroll
        for (int kk = 0; kk < 2; kk++) {
            const int kb = kk * 64 + (lane >> 4) * 16;
            bf16x8 af[4], bfr[4];
#pragma unroll
            for (int mi = 0; mi < 4; mi++) {
                int row = wm * 64 + mi * 16 + (lane & 15);
                af[mi] = *(const bf16x8*)((const char*)lds_a + row * 128 + (kb ^ ((row & 7) << 4)));
            }
#pragma unroll
            for (int nj = 0; nj < 4; nj++) {
                int row = wn * 64 + nj * 16 + (lane & 15);
                bfr[nj] = *(const bf16x8*)((const char*)lds_b + row * 128 + (kb ^ ((row & 7) << 4)));
            }
#pragma unroll
            for (int mi = 0; mi < 4; mi++)
#pragma unroll
                for (int nj = 0; nj < 4; nj++)
                    acc[mi][nj] = __builtin_amdgcn_mfma_f32_16x16x32_bf16(af[mi], bfr[nj], acc[mi][nj], 0, 0, 0);
        }
    }
    // epilogue: out[token] += prob * result
#pragma unroll
    for (int mi = 0; mi < 4; mi++) {
#pragma unroll
        for (int r = 0; r < 4; r++) {
            int row = wm * 64 + mi * 16 + (lane >> 4) * 4 + r;
            int rg = m0 + row;
            if (rg >= n_e) continue;
            int tok = token_list[off + rg];
            float p = prob_list[off + rg];
            size_t obase = (size_t)tok * DD + n0 + wn * 64;
#pragma unroll
            for (int nj = 0; nj < 4; nj++)
                atomicAdd(&out[obase + nj * 16 + (lane & 15)], acc[mi][nj][r] * p);
        }
    }
}

// ================ fallback: round-0 f32-input kernels ================
constexpr int BM = 128, BN = 64, BK = 64;

__global__ __launch_bounds__(256) void k_gateup_fb(
    const float* __restrict__ x,
    const float* __restrict__ gate_w,
    const float* __restrict__ up_w,
    const int* __restrict__ offsets,
    const int* __restrict__ token_list,
    unsigned short* __restrict__ act)
{
    const int e = blockIdx.z;
    const int off = offsets[e];
    const int n_e = offsets[e + 1] - off;
    const int m0 = blockIdx.y * BM;
    if (m0 >= n_e) return;
    const int n0 = blockIdx.x * BN;

    __shared__ unsigned short lds_a[BM * BK];
    __shared__ unsigned short lds_g[BN * BK];
    __shared__ unsigned short lds_u[BN * BK];

    const int tid = threadIdx.x;
    const int lane = tid & 63;
    const int wid = tid >> 6;
    const int wm = wid >> 1, wn = wid & 1;

    const float* gw = gate_w + (size_t)e * HH * DD;
    const float* uw = up_w + (size_t)e * HH * DD;

    const float* arow[8];
    bool arow_ok[8];
#pragma unroll
    for (int p = 0; p < 8; p++) {
        int rg = m0 + (tid >> 4) + p * 16;
        arow_ok[p] = (rg < n_e);
        int tok = arow_ok[p] ? token_list[off + rg] : 0;
        arow[p] = x + (size_t)tok * DD;
    }

    f32x4 accg[4][2] = {};
    f32x4 accu[4][2] = {};

    for (int k0 = 0; k0 < DD; k0 += BK) {
        __syncthreads();
#pragma unroll
        for (int p = 0; p < 8; p++) {
            int row = (tid >> 4) + p * 16;
            int col4 = (tid & 15) * 4;
            ushort4 u4 = make_ushort4(0, 0, 0, 0);
            if (arow_ok[p]) {
                const float4 v = *(const float4*)(arow[p] + k0 + col4);
                u4 = make_ushort4(f2bf(v.x), f2bf(v.y), f2bf(v.z), f2bf(v.w));
            }
            int sw = col4 ^ ((row & 7) << 3);
            *(ushort4*)&lds_a[row * BK + sw] = u4;
        }
#pragma unroll
        for (int p = 0; p < 4; p++) {
            int row = (tid >> 4) + p * 16;
            int col4 = (tid & 15) * 4;
            int sw = col4 ^ ((row & 7) << 3);
            size_t gidx = (size_t)(n0 + row) * DD + k0 + col4;
            {
                const float4 v = *(const float4*)(gw + gidx);
                *(ushort4*)&lds_g[row * BK + sw] =
                    make_ushort4(f2bf(v.x), f2bf(v.y), f2bf(v.z), f2bf(v.w));
            }
            {
                const float4 v = *(const float4*)(uw + gidx);
                *(ushort4*)&lds_u[row * BK + sw] =
                    make_ushort4(f2bf(v.x), f2bf(v.y), f2bf(v.z), f2bf(v.w));
            }
        }
        __syncthreads();
#pragma unroll
        for (int kk = 0; kk < BK; kk += 32) {
            bf16x8 af[4], gf[2], uf[2];
            int kcol = kk + (lane >> 4) * 8;
#pragma unroll
            for (int mi = 0; mi < 4; mi++) {
                int row = wm * 64 + mi * 16 + (lane & 15);
                int sw = kcol ^ ((row & 7) << 3);
                af[mi] = *(const bf16x8*)&lds_a[row * BK + sw];
            }
#pragma unroll
            for (int ni = 0; ni < 2; ni++) {
                int row = wn * 32 + ni * 16 + (lane & 15);
                int sw = kcol ^ ((row & 7) << 3);
                gf[ni] = *(const bf16x8*)&lds_g[row * BK + sw];
                uf[ni] = *(const bf16x8*)&lds_u[row * BK + sw];
            }
#pragma unroll
            for (int mi = 0; mi < 4; mi++)
#pragma unroll
                for (int ni = 0; ni < 2; ni++) {
                    accg[mi][ni] = __builtin_amdgcn_mfma_f32_16x16x32_bf16(af[mi], gf[ni], accg[mi][ni], 0, 0, 0);
                    accu[mi][ni] = __builtin_amdgcn_mfma_f32_16x16x32_bf16(af[mi], uf[ni], accu[mi][ni], 0, 0, 0);
                }
        }
    }
#pragma unroll
    for (int mi = 0; mi < 4; mi++) {
#pragma unroll
        for (int r = 0; r < 4; r++) {
            int row = wm * 64 + mi * 16 + (lane >> 4) * 4 + r;
            int rg = m0 + row;
            if (rg >= n_e) continue;
            size_t rowbase = (size_t)(off + rg) * HH + n0 + wn * 32;
#pragma unroll
            for (int ni = 0; ni < 2; ni++) {
                float g = accg[mi][ni][r];
                float u = accu[mi][ni][r];
                float s = g / (1.f + __expf(-g)) * u;
                act[rowbase + ni * 16 + (lane & 15)] = f2bf(s);
            }
        }
    }
}

__global__ __launch_bounds__(256) void k_down_fb(
    const unsigned short* __restrict__ act,
    const float* __restrict__ down_w,
    const int* __restrict__ offsets,
    const int* __restrict__ token_list,
    const float* __restrict__ prob_list,
    float* __restrict__ out)
{
    const int e = blockIdx.z;
    const int off = offsets[e];
    const int n_e = offsets[e + 1] - off;
    const int m0 = blockIdx.y * BM;
    if (m0 >= n_e) return;
    const int n0 = blockIdx.x * BN;

    __shared__ unsigned short lds_a[BM * BK];
    __shared__ unsigned short lds_b[BN * BK];

    const int tid = threadIdx.x;
    const int lane = tid & 63;
    const int wid = tid >> 6;
    const int wm = wid >> 1, wn = wid & 1;

    const float* dw = down_w + (size_t)e * DD * HH;

    f32x4 acc[4][2] = {};

    for (int k0 = 0; k0 < HH; k0 += BK) {
        __syncthreads();
#pragma unroll
        for (int p = 0; p < 4; p++) {
            int row = (tid >> 3) + p * 32;
            int col8 = (tid & 7) * 8;
            int rg = m0 + row;
            uint4 v = make_uint4(0, 0, 0, 0);
            if (rg < n_e)
                v = *(const uint4*)(act + (size_t)(off + rg) * HH + k0 + col8);
            int sw = col8 ^ ((row & 7) << 3);
            *(uint4*)&lds_a[row * BK + sw] = v;
        }
#pragma unroll
        for (int p = 0; p < 4; p++) {
            int row = (tid >> 4) + p * 16;
            int col4 = (tid & 15) * 4;
            const float4 v = *(const float4*)(dw + (size_t)(n0 + row) * HH + k0 + col4);
            int sw = col4 ^ ((row & 7) << 3);
            *(ushort4*)&lds_b[row * BK + sw] =
                make_ushort4(f2bf(v.x), f2bf(v.y), f2bf(v.z), f2bf(v.w));
        }
        __syncthreads();
#pragma unroll
        for (int kk = 0; kk < BK; kk += 32) {
            bf16x8 af[4], bfrag[2];
            int kcol = kk + (lane >> 4) * 8;
#pragma unroll
            for (int mi = 0; mi < 4; mi++) {
                int row = wm * 64 + mi * 16 + (lane & 15);
                int sw = kcol ^ ((row & 7) << 3);
                af[mi] = *(const bf16x8*)&lds_a[row * BK + sw];
            }
#pragma unroll
            for (int ni = 0; ni < 2; ni++) {
                int row = wn * 32 + ni * 16 + (lane & 15);
                int sw = kcol ^ ((row & 7) << 3);
                bfrag[ni] = *(const bf16x8*)&lds_b[row * BK + sw];
            }
#pragma unroll
            for (int mi = 0; mi < 4; mi++)
#pragma unroll
                for (int ni = 0; ni < 2; ni++)
                    acc[mi][ni] = __builtin_amdgcn_mfma_f32_16x16x32_bf16(af[mi], bfrag[ni], acc[mi][ni], 0, 0, 0);
        }
    }
#pragma unroll
    for (int mi = 0; mi < 4; mi++) {
#pragma unroll
        for (int r = 0; r < 4; r++) {
            int row = wm * 64 + mi * 16 + (lane >> 4) * 4 + r;
            int rg = m0 + row;
            if (rg >= n_e) continue;
            int tok = token_list[off + rg];
            float p = prob_list[off + rg];
            size_t obase = (size_t)tok * DD + n0 + wn * 32;
#pragma unroll
            for (int ni = 0; ni < 2; ni++)
                atomicAdd(&out[obase + ni * 16 + (lane & 15)], acc[mi][ni][r] * p);
        }
    }
}

extern "C" void kernel_launch(void* const* d_in, const int* in_sizes, int n_in,
                              void* d_out, int out_size, void* d_ws, size_t ws_size,
                              hipStream_t stream) {
    const float* x  = (const float*)d_in[0];
    const float* rw = (const float*)d_in[1];
    const float* gw = (const float*)d_in[2];
    const float* uw = (const float*)d_in[3];
    const float* dw = (const float*)d_in[4];
    float* out = (float*)d_out;

    char* ws = (char*)d_ws;
    int*   topk_idx   = (int*)(ws + 0);
    float* topk_prob  = (float*)(ws + 65536);
    int*   counts     = (int*)(ws + 131072);
    int*   cursor     = (int*)(ws + 131104);
    int*   offsets    = (int*)(ws + 131136);
    int*   token_list = (int*)(ws + 131264);
    float* prob_list  = (float*)(ws + 196800);

    hipMemsetAsync(d_out, 0, (size_t)out_size * sizeof(float), stream);
    hipMemsetAsync(ws + 131072, 0, 64, stream);   // counts + cursor

    k_router<<<TOK / 4, 256, 0, stream>>>(x, rw, topk_idx, topk_prob, counts);
    k_scan<<<1, 64, 0, stream>>>(counts, offsets);
    k_scatter<<<TOK / 256, 256, 0, stream>>>(topk_idx, topk_prob, offsets, cursor,
                                             token_list, prob_list);

    const size_t NEED_BIG = 185073664ULL;
    if (ws_size >= NEED_BIG) {
        unsigned short* x_bf  = (unsigned short*)(ws + 524288);
        unsigned short* gw_bf = (unsigned short*)(ws + 17301504);
        unsigned short* uw_bf = (unsigned short*)(ws + 50855936);
        unsigned short* dw_bf = (unsigned short*)(ws + 84410368);
        unsigned short* act   = (unsigned short*)(ws + 117964800);

        k_cvt8<<<2048, 256, 0, stream>>>(x,  x_bf,  (TOK * DD) / 8);
        k_cvt8<<<2048, 256, 0, stream>>>(gw, gw_bf, (NE * HH * DD) / 8);
        k_cvt8<<<2048, 256, 0, stream>>>(uw, uw_bf, (NE * HH * DD) / 8);
        k_cvt8<<<2048, 256, 0, stream>>>(dw, dw_bf, (NE * DD * HH) / 8);

        k_gateup_bf<<<dim3(HH / 64, TOK / 128, NE), 256, 0, stream>>>(
            x_bf, gw_bf, uw_bf, offsets, token_list, act);
        k_down_bf<<<dim3(DD / 128, TOK / 128, NE), 256, 0, stream>>>(
            act, dw_bf, offsets, token_list, prob_list, out);
    } else {
        unsigned short* act = (unsigned short*)(ws + 524288);
        k_gateup_fb<<<dim3(HH / BN, TOK / BM, NE), 256, 0, stream>>>(
            x, gw, uw, offsets, token_list, act);
        k_down_fb<<<dim3(DD / BN, TOK / BM, NE), 256, 0, stream>>>(
            act, dw, offsets, token_list, prob_list, out);
    }
}

// Round 3
// 695.181 us; speedup vs baseline: 1.6037x; 1.0246x over previous
//
#include <hip/hip_runtime.h>

typedef __attribute__((ext_vector_type(4))) float f32x4;
typedef __attribute__((ext_vector_type(8))) short bf16x8;

constexpr int TOK = 8192;   // B*S
constexpr int DD  = 1024;   // D
constexpr int HH  = 2048;   // H
constexpr int NE  = 8;      // experts

// ---- workspace layout (bytes) ----
// 0      topk_idx   int[16384]
// 65536  topk_prob  f32[16384]
// 131072 counts     int[8]
// 131104 cursor     int[8]
// 131136 offsets    int[9]
// 131264 token_list int[16384]
// 196800 prob_list  f32[16384]
// 524288            x_bf   bf16[8192*1024]      (16.8 MB)
// 17301504          gw_bf  bf16[8*2048*1024]    (33.6 MB)
// 50855936          uw_bf  bf16[8*2048*1024]    (33.6 MB)
// 84410368          dw_bf  bf16[8*1024*2048]    (33.6 MB)
// 117964800         act    bf16[16384*2048]     (67.1 MB)
// total need: 185,073,664 B

__device__ __forceinline__ unsigned short f2bf(float f) {
    union { float f; unsigned u; } v; v.f = f;
    unsigned r = v.u + 0x7fffu + ((v.u >> 16) & 1u);   // RNE
    return (unsigned short)(r >> 16);
}

__device__ __forceinline__ void gl2lds16(const void* g, void* l) {
    __builtin_amdgcn_global_load_lds(
        (const __attribute__((address_space(1))) unsigned int*)g,
        (__attribute__((address_space(3))) unsigned int*)l, 16, 0, 0);
}

// ------------- router: logits, top-2, probs; also emits x in bf16 -------------
__global__ __launch_bounds__(256) void k_router(
    const float* __restrict__ x, const float* __restrict__ rw,
    int* __restrict__ topk_idx, float* __restrict__ topk_prob,
    int* __restrict__ counts, unsigned short* __restrict__ x_bf)
{
    int wave = threadIdx.x >> 6;
    int lane = threadIdx.x & 63;
    int t = blockIdx.x * 4 + wave;

    const float4* xr = (const float4*)(x + (size_t)t * DD);
    float4 xv[4];
#pragma unroll
    for (int i = 0; i < 4; i++) xv[i] = xr[lane + 64 * i];

    // fused f32->bf16 conversion of x (x is fully read here anyway)
#pragma unroll
    for (int i = 0; i < 4; i++) {
        ushort4 u4 = make_ushort4(f2bf(xv[i].x), f2bf(xv[i].y),
                                  f2bf(xv[i].z), f2bf(xv[i].w));
        *(ushort4*)(x_bf + (size_t)t * DD + (lane + 64 * i) * 4) = u4;
    }

    float acc[NE];
#pragma unroll
    for (int e = 0; e < NE; e++) {
        const float4* wr = (const float4*)(rw + (size_t)e * DD);
        float s = 0.f;
#pragma unroll
        for (int i = 0; i < 4; i++) {
            float4 w = wr[lane + 64 * i];
            s += xv[i].x * w.x + xv[i].y * w.y + xv[i].z * w.z + xv[i].w * w.w;
        }
        acc[e] = s;
    }
#pragma unroll
    for (int e = 0; e < NE; e++) {
        float s = acc[e];
        for (int m = 32; m >= 1; m >>= 1) s += __shfl_xor(s, m);
        acc[e] = s;
    }
    if (lane == 0) {
        int b0 = 0; float l0 = acc[0];
#pragma unroll
        for (int e = 1; e < NE; e++) if (acc[e] > l0) { l0 = acc[e]; b0 = e; }
        int b1 = -1; float l1 = -3.0e38f;
#pragma unroll
        for (int e = 0; e < NE; e++) if (e != b0 && acc[e] > l1) { l1 = acc[e]; b1 = e; }
        float p0 = 1.f / (1.f + __expf(l1 - l0));
        float p1 = 1.f - p0;
        topk_idx[t * 2 + 0] = b0;  topk_idx[t * 2 + 1] = b1;
        topk_prob[t * 2 + 0] = p0; topk_prob[t * 2 + 1] = p1;
        atomicAdd(&counts[b0], 1);
        atomicAdd(&counts[b1], 1);
    }
}

__global__ void k_scan(const int* __restrict__ counts, int* __restrict__ offsets) {
    if (threadIdx.x == 0) {
        int s = 0;
        for (int e = 0; e < NE; e++) { offsets[e] = s; s += counts[e]; }
        offsets[NE] = s;
    }
}

__global__ __launch_bounds__(256) void k_scatter(
    const int* __restrict__ topk_idx, const float* __restrict__ topk_prob,
    const int* __restrict__ offsets, int* __restrict__ cursor,
    int* __restrict__ token_list, float* __restrict__ prob_list)
{
    int t = blockIdx.x * 256 + threadIdx.x;
#pragma unroll
    for (int k = 0; k < 2; k++) {
        int e = topk_idx[t * 2 + k];
        float p = topk_prob[t * 2 + k];
        int pos = atomicAdd(&cursor[e], 1);
        token_list[offsets[e] + pos] = t;
        prob_list[offsets[e] + pos] = p;
    }
}

// ---------------- f32 -> bf16 bulk convert ----------------
__global__ __launch_bounds__(256) void k_cvt8(
    const float* __restrict__ in, unsigned short* __restrict__ out, int n8)
{
    int i = blockIdx.x * blockDim.x + threadIdx.x;
    int stride = gridDim.x * blockDim.x;
    for (; i < n8; i += stride) {
        const float4* p = (const float4*)(in + (size_t)i * 8);
        float4 a = p[0], b = p[1];
        uint4 v;
        v.x = (unsigned)f2bf(a.x) | ((unsigned)f2bf(a.y) << 16);
        v.y = (unsigned)f2bf(a.z) | ((unsigned)f2bf(a.w) << 16);
        v.z = (unsigned)f2bf(b.x) | ((unsigned)f2bf(b.y) << 16);
        v.w = (unsigned)f2bf(b.z) | ((unsigned)f2bf(b.w) << 16);
        *(uint4*)(out + (size_t)i * 8) = v;
    }
}

// ================ gateup: BM=128 x BN=128 (gate AND up), BK=64 ================
// 512 thr / 8 waves (4x2); wave tile 32x64 per output. Double-buffered LDS
// (96 KB dynamic): prefetch next K-tile via global_load_lds while MFMA runs.
__global__ __launch_bounds__(512) void k_gateup_v2(
    const unsigned short* __restrict__ xb,
    const unsigned short* __restrict__ gwb,
    const unsigned short* __restrict__ uwb,
    const int* __restrict__ offsets,
    const int* __restrict__ token_list,
    unsigned short* __restrict__ act)
{
    extern __shared__ char lds[];   // [2][49152]: A 16K | G 16K | U 16K per buf

    const int e = blockIdx.z;
    const int off = offsets[e];
    const int n_e = offsets[e + 1] - off;
    const int m0 = blockIdx.y * 128;
    if (m0 >= n_e) return;
    const int n0 = blockIdx.x * 128;

    const int tid = threadIdx.x, lane = tid & 63, wid = tid >> 6;
    const int wm = wid >> 1, wn = wid & 1;          // 4 x 2 wave grid
    const int l8 = lane >> 3;                        // row within 8-row chunk
    const int colb = ((lane & 7) * 16) ^ (l8 << 4);  // pre-swizzled src col byte

    // 48 chunks/K-step: [A:0..15][G:16..31][U:32..47]; this wave stages 6.
    const char* src[6];
    unsigned ldsoff[6];
#pragma unroll
    for (int i = 0; i < 6; i++) {
        int c = wid * 6 + i;
        int region = c >> 4;       // 0=A 1=G 2=U
        int sub = c & 15;
        ldsoff[i] = region * 16384u + sub * 1024u;
        int row8 = sub * 8 + l8;
        if (region == 0) {
            int rg = m0 + row8; if (rg > n_e - 1) rg = n_e - 1;
            int tok = token_list[off + rg];
            src[i] = (const char*)xb + (size_t)tok * (DD * 2) + colb;
        } else {
            const unsigned short* w = (region == 1) ? gwb : uwb;
            src[i] = (const char*)w + ((size_t)e * HH + n0 + row8) * (DD * 2) + colb;
        }
    }

    f32x4 accg[2][4] = {};
    f32x4 accu[2][4] = {};

    // prologue: stage K-step 0 into buf 0
#pragma unroll
    for (int i = 0; i < 6; i++) gl2lds16(src[i], lds + ldsoff[i]);
    __syncthreads();

    unsigned cur = 0;
    constexpr int NSTEP = (DD * 2) / 128;   // 16
    for (int t = 0; t < NSTEP; ++t) {
        if (t + 1 < NSTEP) {
            char* b = lds + (cur ^ 1u) * 49152u;
#pragma unroll
            for (int i = 0; i < 6; i++) gl2lds16(src[i] + (t + 1) * 128, b + ldsoff[i]);
        }
        const char* La = lds + cur * 49152u;
        const char* Lg = La + 16384;
        const char* Lu = La + 32768;
#pragma unroll
        for (int kk = 0; kk < 2; kk++) {
            const int kb = kk * 64 + (lane >> 4) * 16;
            bf16x8 af[2], gf[4], uf[4];
#pragma unroll
            for (int mi = 0; mi < 2; mi++) {
                int row = wm * 32 + mi * 16 + (lane & 15);
                af[mi] = *(const bf16x8*)(La + row * 128 + (kb ^ ((row & 7) << 4)));
            }
#pragma unroll
            for (int nj = 0; nj < 4; nj++) {
                int row = wn * 64 + nj * 16 + (lane & 15);
                int ad = row * 128 + (kb ^ ((row & 7) << 4));
                gf[nj] = *(const bf16x8*)(Lg + ad);
                uf[nj] = *(const bf16x8*)(Lu + ad);
            }
#pragma unroll
            for (int mi = 0; mi < 2; mi++)
#pragma unroll
                for (int nj = 0; nj < 4; nj++) {
                    accg[mi][nj] = __builtin_amdgcn_mfma_f32_16x16x32_bf16(af[mi], gf[nj], accg[mi][nj], 0, 0, 0);
                    accu[mi][nj] = __builtin_amdgcn_mfma_f32_16x16x32_bf16(af[mi], uf[nj], accu[mi][nj], 0, 0, 0);
                }
        }
        __syncthreads();   // drains vmcnt: next buffer staged; cur free to overwrite
        cur ^= 1u;
    }

    // epilogue: silu(g)*u -> act bf16
#pragma unroll
    for (int mi = 0; mi < 2; mi++) {
#pragma unroll
        for (int r = 0; r < 4; r++) {
            int row = wm * 32 + mi * 16 + (lane >> 4) * 4 + r;
            int rg = m0 + row;
            if (rg >= n_e) continue;
            size_t rowbase = (size_t)(off + rg) * HH + n0 + wn * 64;
#pragma unroll
            for (int nj = 0; nj < 4; nj++) {
                float g = accg[mi][nj][r];
                float u = accu[mi][nj][r];
                float s = g / (1.f + __expf(-g)) * u;
                act[rowbase + nj * 16 + (lane & 15)] = f2bf(s);
            }
        }
    }
}

// ================ down: BM=128 x BN=128, BK=64, dbuf 64 KB ================
__global__ __launch_bounds__(512) void k_down_v2(
    const unsigned short* __restrict__ act,
    const unsigned short* __restrict__ dwb,
    const int* __restrict__ offsets,
    const int* __restrict__ token_list,
    const float* __restrict__ prob_list,
    float* __restrict__ out)
{
    __shared__ char lds[65536];   // [2][32768]: A 16K | B 16K per buf

    const int e = blockIdx.z;
    const int off = offsets[e];
    const int n_e = offsets[e + 1] - off;
    const int m0 = blockIdx.y * 128;
    if (m0 >= n_e) return;
    const int n0 = blockIdx.x * 128;   // D cols

    const int tid = threadIdx.x, lane = tid & 63, wid = tid >> 6;
    const int wm = wid >> 1, wn = wid & 1;
    const int l8 = lane >> 3;
    const int colb = ((lane & 7) * 16) ^ (l8 << 4);

    // 32 chunks/K-step: [A:0..15][B:16..31]; this wave stages 4.
    const char* src[4];
    unsigned ldsoff[4];
#pragma unroll
    for (int i = 0; i < 4; i++) {
        int c = wid * 4 + i;
        int region = c >> 4;
        int sub = c & 15;
        ldsoff[i] = region * 16384u + sub * 1024u;
        int row8 = sub * 8 + l8;
        if (region == 0) {
            int rg = m0 + row8; if (rg > n_e - 1) rg = n_e - 1;
            src[i] = (const char*)act + (size_t)(off + rg) * (HH * 2) + colb;
        } else {
            src[i] = (const char*)dwb + ((size_t)e * DD + n0 + row8) * (HH * 2) + colb;
        }
    }

    f32x4 acc[2][4] = {};

#pragma unroll
    for (int i = 0; i < 4; i++) gl2lds16(src[i], lds + ldsoff[i]);
    __syncthreads();

    unsigned cur = 0;
    constexpr int NSTEP = (HH * 2) / 128;   // 32
    for (int t = 0; t < NSTEP; ++t) {
        if (t + 1 < NSTEP) {
            char* b = lds + (cur ^ 1u) * 32768u;
#pragma unroll
            for (int i = 0; i < 4; i++) gl2lds16(src[i] + (t + 1) * 128, b + ldsoff[i]);
        }
        const char* La = lds + cur * 32768u;
        const char* Lb = La + 16384;
#pragma unroll
        for (int kk = 0; kk < 2; kk++) {
            const int kb = kk * 64 + (lane >> 4) * 16;
            bf16x8 af[2], bfr[4];
#pragma unroll
            for (int mi = 0; mi < 2; mi++) {
                int row = wm * 32 + mi * 16 + (lane & 15);
                af[mi] = *(const bf16x8*)(La + row * 128 + (kb ^ ((row & 7) << 4)));
            }
#pragma unroll
            for (int nj = 0; nj < 4; nj++) {
                int row = wn * 64 + nj * 16 + (lane & 15);
                bfr[nj] = *(const bf16x8*)(Lb + row * 128 + (kb ^ ((row & 7) << 4)));
            }
#pragma unroll
            for (int mi = 0; mi < 2; mi++)
#pragma unroll
                for (int nj = 0; nj < 4; nj++)
                    acc[mi][nj] = __builtin_amdgcn_mfma_f32_16x16x32_bf16(af[mi], bfr[nj], acc[mi][nj], 0, 0, 0);
        }
        __syncthreads();
        cur ^= 1u;
    }

    // epilogue: out[token] += prob * result
#pragma unroll
    for (int mi = 0; mi < 2; mi++) {
#pragma unroll
        for (int r = 0; r < 4; r++) {
            int row = wm * 32 + mi * 16 + (lane >> 4) * 4 + r;
            int rg = m0 + row;
            if (rg >= n_e) continue;
            int tok = token_list[off + rg];
            float p = prob_list[off + rg];
            size_t obase = (size_t)tok * DD + n0 + wn * 64;
#pragma unroll
            for (int nj = 0; nj < 4; nj++)
                atomicAdd(&out[obase + nj * 16 + (lane & 15)], acc[mi][nj][r] * p);
        }
    }
}

extern "C" void kernel_launch(void* const* d_in, const int* in_sizes, int n_in,
                              void* d_out, int out_size, void* d_ws, size_t ws_size,
                              hipStream_t stream) {
    const float* x  = (const float*)d_in[0];
    const float* rw = (const float*)d_in[1];
    const float* gw = (const float*)d_in[2];
    const float* uw = (const float*)d_in[3];
    const float* dw = (const float*)d_in[4];
    float* out = (float*)d_out;

    char* ws = (char*)d_ws;
    int*   topk_idx   = (int*)(ws + 0);
    float* topk_prob  = (float*)(ws + 65536);
    int*   counts     = (int*)(ws + 131072);
    int*   cursor     = (int*)(ws + 131104);
    int*   offsets    = (int*)(ws + 131136);
    int*   token_list = (int*)(ws + 131264);
    float* prob_list  = (float*)(ws + 196800);

    unsigned short* x_bf  = (unsigned short*)(ws + 524288);
    unsigned short* gw_bf = (unsigned short*)(ws + 17301504);
    unsigned short* uw_bf = (unsigned short*)(ws + 50855936);
    unsigned short* dw_bf = (unsigned short*)(ws + 84410368);
    unsigned short* act   = (unsigned short*)(ws + 117964800);

    hipMemsetAsync(d_out, 0, (size_t)out_size * sizeof(float), stream);
    hipMemsetAsync(ws + 131072, 0, 64, stream);   // counts + cursor

    k_router<<<TOK / 4, 256, 0, stream>>>(x, rw, topk_idx, topk_prob, counts, x_bf);
    k_scan<<<1, 64, 0, stream>>>(counts, offsets);
    k_scatter<<<TOK / 256, 256, 0, stream>>>(topk_idx, topk_prob, offsets, cursor,
                                             token_list, prob_list);

    k_cvt8<<<2048, 256, 0, stream>>>(gw, gw_bf, (NE * HH * DD) / 8);
    k_cvt8<<<2048, 256, 0, stream>>>(uw, uw_bf, (NE * HH * DD) / 8);
    k_cvt8<<<2048, 256, 0, stream>>>(dw, dw_bf, (NE * DD * HH) / 8);

    k_gateup_v2<<<dim3(HH / 128, TOK / 128, NE), 512, 98304, stream>>>(
        x_bf, gw_bf, uw_bf, offsets, token_list, act);
    k_down_v2<<<dim3(DD / 128, TOK / 128, NE), 512, 0, stream>>>(
        act, dw_bf, offsets, token_list, prob_list, out);
}

// Round 4
// 680.395 us; speedup vs baseline: 1.6386x; 1.0217x over previous
//
#include <hip/hip_runtime.h>

typedef __attribute__((ext_vector_type(4))) float f32x4;
typedef __attribute__((ext_vector_type(8))) short bf16x8;

constexpr int TOK = 8192;   // B*S
constexpr int DD  = 1024;   // D
constexpr int HH  = 2048;   // H
constexpr int NE  = 8;      // experts

// ---- workspace layout (bytes) ----
// 0      topk_idx   int[16384]
// 65536  topk_prob  f32[16384]
// 131072 counts     int[8]
// 131104 cursor     int[8]
// 131136 offsets    int[9]
// 131264 token_list int[16384]
// 196800 prob_list  f32[16384]
// 524288            x_bf   bf16[8192*1024]      (16.8 MB)
// 17301504          gw_bf  bf16[8*2048*1024]    (33.6 MB)
// 50855936          uw_bf  bf16[8*2048*1024]    (33.6 MB)
// 84410368          dw_bf  bf16[8*1024*2048]    (33.6 MB)
// 117964800         act    bf16[16384*2048]     (67.1 MB)
// total need: 185,073,664 B

__device__ __forceinline__ unsigned short f2bf(float f) {
    union { float f; unsigned u; } v; v.f = f;
    unsigned r = v.u + 0x7fffu + ((v.u >> 16) & 1u);   // RNE
    return (unsigned short)(r >> 16);
}

__device__ __forceinline__ void gl2lds16(const void* g, void* l) {
    __builtin_amdgcn_global_load_lds(
        (const __attribute__((address_space(1))) unsigned int*)g,
        (__attribute__((address_space(3))) unsigned int*)l, 16, 0, 0);
}

// ------------- router: logits, top-2, probs; also emits x in bf16 -------------
__global__ __launch_bounds__(256) void k_router(
    const float* __restrict__ x, const float* __restrict__ rw,
    int* __restrict__ topk_idx, float* __restrict__ topk_prob,
    int* __restrict__ counts, unsigned short* __restrict__ x_bf)
{
    int wave = threadIdx.x >> 6;
    int lane = threadIdx.x & 63;
    int t = blockIdx.x * 4 + wave;

    const float4* xr = (const float4*)(x + (size_t)t * DD);
    float4 xv[4];
#pragma unroll
    for (int i = 0; i < 4; i++) xv[i] = xr[lane + 64 * i];

#pragma unroll
    for (int i = 0; i < 4; i++) {
        ushort4 u4 = make_ushort4(f2bf(xv[i].x), f2bf(xv[i].y),
                                  f2bf(xv[i].z), f2bf(xv[i].w));
        *(ushort4*)(x_bf + (size_t)t * DD + (lane + 64 * i) * 4) = u4;
    }

    float acc[NE];
#pragma unroll
    for (int e = 0; e < NE; e++) {
        const float4* wr = (const float4*)(rw + (size_t)e * DD);
        float s = 0.f;
#pragma unroll
        for (int i = 0; i < 4; i++) {
            float4 w = wr[lane + 64 * i];
            s += xv[i].x * w.x + xv[i].y * w.y + xv[i].z * w.z + xv[i].w * w.w;
        }
        acc[e] = s;
    }
#pragma unroll
    for (int e = 0; e < NE; e++) {
        float s = acc[e];
        for (int m = 32; m >= 1; m >>= 1) s += __shfl_xor(s, m);
        acc[e] = s;
    }
    if (lane == 0) {
        int b0 = 0; float l0 = acc[0];
#pragma unroll
        for (int e = 1; e < NE; e++) if (acc[e] > l0) { l0 = acc[e]; b0 = e; }
        int b1 = -1; float l1 = -3.0e38f;
#pragma unroll
        for (int e = 0; e < NE; e++) if (e != b0 && acc[e] > l1) { l1 = acc[e]; b1 = e; }
        float p0 = 1.f / (1.f + __expf(l1 - l0));
        float p1 = 1.f - p0;
        topk_idx[t * 2 + 0] = b0;  topk_idx[t * 2 + 1] = b1;
        topk_prob[t * 2 + 0] = p0; topk_prob[t * 2 + 1] = p1;
        atomicAdd(&counts[b0], 1);
        atomicAdd(&counts[b1], 1);
    }
}

__global__ void k_scan(const int* __restrict__ counts, int* __restrict__ offsets) {
    if (threadIdx.x == 0) {
        int s = 0;
        for (int e = 0; e < NE; e++) { offsets[e] = s; s += counts[e]; }
        offsets[NE] = s;
    }
}

__global__ __launch_bounds__(256) void k_scatter(
    const int* __restrict__ topk_idx, const float* __restrict__ topk_prob,
    const int* __restrict__ offsets, int* __restrict__ cursor,
    int* __restrict__ token_list, float* __restrict__ prob_list)
{
    int t = blockIdx.x * 256 + threadIdx.x;
#pragma unroll
    for (int k = 0; k < 2; k++) {
        int e = topk_idx[t * 2 + k];
        float p = topk_prob[t * 2 + k];
        int pos = atomicAdd(&cursor[e], 1);
        token_list[offsets[e] + pos] = t;
        prob_list[offsets[e] + pos] = p;
    }
}

// ---------------- f32 -> bf16 bulk convert ----------------
__global__ __launch_bounds__(256) void k_cvt8(
    const float* __restrict__ in, unsigned short* __restrict__ out, int n8)
{
    int i = blockIdx.x * blockDim.x + threadIdx.x;
    int stride = gridDim.x * blockDim.x;
    for (; i < n8; i += stride) {
        const float4* p = (const float4*)(in + (size_t)i * 8);
        float4 a = p[0], b = p[1];
        uint4 v;
        v.x = (unsigned)f2bf(a.x) | ((unsigned)f2bf(a.y) << 16);
        v.y = (unsigned)f2bf(a.z) | ((unsigned)f2bf(a.w) << 16);
        v.z = (unsigned)f2bf(b.x) | ((unsigned)f2bf(b.y) << 16);
        v.w = (unsigned)f2bf(b.z) | ((unsigned)f2bf(b.w) << 16);
        *(uint4*)(out + (size_t)i * 8) = v;
    }
}

// ================ gateup v3: BM=128, B-rows=256 (g128+u128), BK=64 ================
// Ring-3 LDS (3 x 48 KB), depth-2 prefetch, counted vmcnt(6), raw s_barrier.
// 512 thr / 8 waves (2m x 4n); wave = 64 rows x 64 B-rows (32 gate + 32 up cols).
// XCD-grouped mapping: all m-blocks of one (e, n-slice) on the same XCD.
__global__ __launch_bounds__(512) void k_gateup_v3(
    const unsigned short* __restrict__ xb,
    const unsigned short* __restrict__ gwb,
    const unsigned short* __restrict__ uwb,
    const int* __restrict__ offsets,
    const int* __restrict__ token_list,
    unsigned short* __restrict__ act)
{
    extern __shared__ char lds[];   // 3 * 49152: per buf A 16K | B(G+U interleaved) 32K

    const int bid = blockIdx.x;
    const int xcd = bid & 7;
    const int s   = bid >> 3;
    const int m   = s & 127;            // m-tile within group
    const int g   = (s >> 7) * 8 + xcd; // group = e*16 + n  (0..127)
    const int e   = g >> 4;
    const int n   = g & 15;
    const int off = offsets[e];
    const int n_e = offsets[e + 1] - off;
    const int m0  = m * 128;
    if (m0 >= n_e) return;
    const int n0g = n * 128;            // gate/up col base

    const int tid = threadIdx.x, lane = tid & 63, wid = tid >> 6;
    const int wm = wid >> 2, wn = wid & 3;          // 2m x 4n
    const int l8 = lane >> 3;
    const int colb = ((lane & 7) * 16) ^ (l8 << 4); // pre-swizzled source col byte

    // 48 chunks (1 KB each) per K-tile: A:0..15, B:16..47. This wave stages 6.
    const char* src[6];
    unsigned ldsoff[6];
#pragma unroll
    for (int i = 0; i < 6; i++) {
        int c = wid * 6 + i;
        if (c < 16) {
            int tr = c * 8 + l8;
            int rg = m0 + tr; if (rg > n_e - 1) rg = n_e - 1;
            int tok = token_list[off + rg];
            src[i] = (const char*)xb + (size_t)tok * (DD * 2) + colb;
            ldsoff[i] = c * 1024u;
        } else {
            // B-tile row tr in 0..255: wave wn owns rows [wn*64, wn*64+64):
            //   first 32 = gate cols n0g+wn*32+[0,32), next 32 = up cols same range
            int cb = c - 16;
            int tr = cb * 8 + l8;
            int wr = tr >> 6, w = tr & 63;
            const unsigned short* W = (w < 32) ? gwb : uwb;
            int wcol = n0g + wr * 32 + (w & 31);
            src[i] = (const char*)W + ((size_t)e * HH + wcol) * (DD * 2) + colb;
            ldsoff[i] = 16384u + cb * 1024u;
        }
    }

    f32x4 acc[4][4] = {};   // [mi][nj]: nj 0,1 = gate, nj 2,3 = up

#define GU_STAGE(T) do { char* b_ = lds + ((T) % 3) * 49152u; \
    _Pragma("unroll") for (int i_ = 0; i_ < 6; i_++) \
        gl2lds16(src[i_] + (T) * 128, b_ + ldsoff[i_]); } while (0)

    GU_STAGE(0);
    GU_STAGE(1);
    asm volatile("s_waitcnt vmcnt(6)" ::: "memory");   // tile 0 landed (own wave)
    __builtin_amdgcn_s_barrier();
    asm volatile("" ::: "memory");

    constexpr int NT = (DD * 2) / 128;   // 16 K-tiles
    for (int t = 0; t < NT; ++t) {
        if (t + 2 < NT) GU_STAGE(t + 2);
        const char* La = lds + (t % 3) * 49152u;
        const char* Lb = La + 16384;
        __builtin_amdgcn_s_setprio(1);
#pragma unroll
        for (int kk = 0; kk < 2; kk++) {
            const int kb = kk * 64 + (lane >> 4) * 16;
            bf16x8 af[4], bfr[4];
#pragma unroll
            for (int mi = 0; mi < 4; mi++) {
                int row = wm * 64 + mi * 16 + (lane & 15);
                af[mi] = *(const bf16x8*)(La + row * 128 + (kb ^ ((row & 7) << 4)));
            }
#pragma unroll
            for (int nj = 0; nj < 4; nj++) {
                int br = wn * 64 + nj * 16 + (lane & 15);
                bfr[nj] = *(const bf16x8*)(Lb + br * 128 + (kb ^ ((br & 7) << 4)));
            }
#pragma unroll
            for (int mi = 0; mi < 4; mi++)
#pragma unroll
                for (int nj = 0; nj < 4; nj++)
                    acc[mi][nj] = __builtin_amdgcn_mfma_f32_16x16x32_bf16(af[mi], bfr[nj], acc[mi][nj], 0, 0, 0);
        }
        __builtin_amdgcn_s_setprio(0);
        // counted wait: tile t+1 must be landed; tile t+2 stays in flight
        if (t + 2 < NT)      asm volatile("s_waitcnt vmcnt(6)" ::: "memory");
        else if (t + 1 < NT) asm volatile("s_waitcnt vmcnt(0)" ::: "memory");
        __builtin_amdgcn_s_barrier();
        asm volatile("" ::: "memory");
    }
#undef GU_STAGE

    // epilogue: silu(g)*u -> act bf16
#pragma unroll
    for (int mi = 0; mi < 4; mi++) {
#pragma unroll
        for (int r = 0; r < 4; r++) {
            int row = wm * 64 + mi * 16 + (lane >> 4) * 4 + r;
            int rg = m0 + row;
            if (rg >= n_e) continue;
            size_t rowbase = (size_t)(off + rg) * HH + n0g + wn * 32;
#pragma unroll
            for (int nj = 0; nj < 2; nj++) {
                float gg = acc[mi][nj][r];
                float uu = acc[mi][nj + 2][r];
                float sv = gg / (1.f + __expf(-gg)) * uu;
                act[rowbase + nj * 16 + (lane & 15)] = f2bf(sv);
            }
        }
    }
}

// ================ down v3: BM=128, BN=256, BK=64, ring-3 + counted vmcnt ================
__global__ __launch_bounds__(512) void k_down_v3(
    const unsigned short* __restrict__ act,
    const unsigned short* __restrict__ dwb,
    const int* __restrict__ offsets,
    const int* __restrict__ token_list,
    const float* __restrict__ prob_list,
    float* __restrict__ out)
{
    extern __shared__ char lds[];   // 3 * 49152: per buf A 16K | B 32K

    const int bid = blockIdx.x;
    const int xcd = bid & 7;
    const int s   = bid >> 3;
    const int m   = s & 127;
    const int g   = (s >> 7) * 8 + xcd;   // group = e*4 + n (0..31)
    const int e   = g >> 2;
    const int n   = g & 3;
    const int off = offsets[e];
    const int n_e = offsets[e + 1] - off;
    const int m0  = m * 128;
    if (m0 >= n_e) return;
    const int n0  = n * 256;              // D col base

    const int tid = threadIdx.x, lane = tid & 63, wid = tid >> 6;
    const int wm = wid >> 2, wn = wid & 3;
    const int l8 = lane >> 3;
    const int colb = ((lane & 7) * 16) ^ (l8 << 4);

    const char* src[6];
    unsigned ldsoff[6];
#pragma unroll
    for (int i = 0; i < 6; i++) {
        int c = wid * 6 + i;
        if (c < 16) {
            int tr = c * 8 + l8;
            int rg = m0 + tr; if (rg > n_e - 1) rg = n_e - 1;
            src[i] = (const char*)act + (size_t)(off + rg) * (HH * 2) + colb;
            ldsoff[i] = c * 1024u;
        } else {
            int cb = c - 16;
            int tr = cb * 8 + l8;
            src[i] = (const char*)dwb + ((size_t)e * DD + n0 + tr) * (HH * 2) + colb;
            ldsoff[i] = 16384u + cb * 1024u;
        }
    }

    f32x4 acc[4][4] = {};

#define DN_STAGE(T) do { char* b_ = lds + ((T) % 3) * 49152u; \
    _Pragma("unroll") for (int i_ = 0; i_ < 6; i_++) \
        gl2lds16(src[i_] + (T) * 128, b_ + ldsoff[i_]); } while (0)

    DN_STAGE(0);
    DN_STAGE(1);
    asm volatile("s_waitcnt vmcnt(6)" ::: "memory");
    __builtin_amdgcn_s_barrier();
    asm volatile("" ::: "memory");

    constexpr int NT = (HH * 2) / 128;   // 32 K-tiles
    for (int t = 0; t < NT; ++t) {
        if (t + 2 < NT) DN_STAGE(t + 2);
        const char* La = lds + (t % 3) * 49152u;
        const char* Lb = La + 16384;
        __builtin_amdgcn_s_setprio(1);
#pragma unroll
        for (int kk = 0; kk < 2; kk++) {
            const int kb = kk * 64 + (lane >> 4) * 16;
            bf16x8 af[4], bfr[4];
#pragma unroll
            for (int mi = 0; mi < 4; mi++) {
                int row = wm * 64 + mi * 16 + (lane & 15);
                af[mi] = *(const bf16x8*)(La + row * 128 + (kb ^ ((row & 7) << 4)));
            }
#pragma unroll
            for (int nj = 0; nj < 4; nj++) {
                int br = wn * 64 + nj * 16 + (lane & 15);
                bfr[nj] = *(const bf16x8*)(Lb + br * 128 + (kb ^ ((br & 7) << 4)));
            }
#pragma unroll
            for (int mi = 0; mi < 4; mi++)
#pragma unroll
                for (int nj = 0; nj < 4; nj++)
                    acc[mi][nj] = __builtin_amdgcn_mfma_f32_16x16x32_bf16(af[mi], bfr[nj], acc[mi][nj], 0, 0, 0);
        }
        __builtin_amdgcn_s_setprio(0);
        if (t + 2 < NT)      asm volatile("s_waitcnt vmcnt(6)" ::: "memory");
        else if (t + 1 < NT) asm volatile("s_waitcnt vmcnt(0)" ::: "memory");
        __builtin_amdgcn_s_barrier();
        asm volatile("" ::: "memory");
    }
#undef DN_STAGE

    // epilogue: out[token] += prob * result
#pragma unroll
    for (int mi = 0; mi < 4; mi++) {
#pragma unroll
        for (int r = 0; r < 4; r++) {
            int row = wm * 64 + mi * 16 + (lane >> 4) * 4 + r;
            int rg = m0 + row;
            if (rg >= n_e) continue;
            int tok = token_list[off + rg];
            float p = prob_list[off + rg];
            size_t obase = (size_t)tok * DD + n0 + wn * 64;
#pragma unroll
            for (int nj = 0; nj < 4; nj++)
                atomicAdd(&out[obase + nj * 16 + (lane & 15)], acc[mi][nj][r] * p);
        }
    }
}

extern "C" void kernel_launch(void* const* d_in, const int* in_sizes, int n_in,
                              void* d_out, int out_size, void* d_ws, size_t ws_size,
                              hipStream_t stream) {
    const float* x  = (const float*)d_in[0];
    const float* rw = (const float*)d_in[1];
    const float* gw = (const float*)d_in[2];
    const float* uw = (const float*)d_in[3];
    const float* dw = (const float*)d_in[4];
    float* out = (float*)d_out;

    char* ws = (char*)d_ws;
    int*   topk_idx   = (int*)(ws + 0);
    float* topk_prob  = (float*)(ws + 65536);
    int*   counts     = (int*)(ws + 131072);
    int*   cursor     = (int*)(ws + 131104);
    int*   offsets    = (int*)(ws + 131136);
    int*   token_list = (int*)(ws + 131264);
    float* prob_list  = (float*)(ws + 196800);

    unsigned short* x_bf  = (unsigned short*)(ws + 524288);
    unsigned short* gw_bf = (unsigned short*)(ws + 17301504);
    unsigned short* uw_bf = (unsigned short*)(ws + 50855936);
    unsigned short* dw_bf = (unsigned short*)(ws + 84410368);
    unsigned short* act   = (unsigned short*)(ws + 117964800);

    hipMemsetAsync(d_out, 0, (size_t)out_size * sizeof(float), stream);
    hipMemsetAsync(ws + 131072, 0, 64, stream);   // counts + cursor

    k_router<<<TOK / 4, 256, 0, stream>>>(x, rw, topk_idx, topk_prob, counts, x_bf);
    k_scan<<<1, 64, 0, stream>>>(counts, offsets);
    k_scatter<<<TOK / 256, 256, 0, stream>>>(topk_idx, topk_prob, offsets, cursor,
                                             token_list, prob_list);

    k_cvt8<<<2048, 256, 0, stream>>>(gw, gw_bf, (NE * HH * DD) / 8);
    k_cvt8<<<2048, 256, 0, stream>>>(uw, uw_bf, (NE * HH * DD) / 8);
    k_cvt8<<<2048, 256, 0, stream>>>(dw, dw_bf, (NE * DD * HH) / 8);

    // gateup: 128 groups (e*16+n) x 128 worst-case m-tiles, XCD-grouped
    k_gateup_v3<<<16384, 512, 147456, stream>>>(x_bf, gw_bf, uw_bf, offsets,
                                                token_list, act);
    // down: 32 groups (e*4+n) x 128 worst-case m-tiles
    k_down_v3<<<4096, 512, 147456, stream>>>(act, dw_bf, offsets, token_list,
                                             prob_list, out);
}

// Round 6
// 639.992 us; speedup vs baseline: 1.7420x; 1.0631x over previous
//
#include <hip/hip_runtime.h>

typedef __attribute__((ext_vector_type(4))) float f32x4;
typedef __attribute__((ext_vector_type(8))) short bf16x8;

constexpr int TOK = 8192;   // B*S
constexpr int DD  = 1024;   // D
constexpr int HH  = 2048;   // H
constexpr int NE  = 8;      // experts

// ---- workspace layout (bytes) ----
// 0      topk_idx   int[16384]        [0, 65536)
// 65536  topk_prob  f32[16384]        [65536, 131072)
// 131072 counts     int[8]; 131104 cursor int[8]; 131136 offsets int[9]
// 131264 token_list int[16384]        [131264, 196800)
// 196800 slot       int[16384]        [196800, 262336)
// 524288            x_bf   bf16[8192*1024]      (16.8 MB)  [dead after gateup]
// 524288            y      f32[16384*1024]      (67.1 MB)  [overlays x_bf/gw_bf/uw_bf; written by down]
// 17301504          gw_bf  bf16[8*2048*1024]    (33.6 MB)  [dead after gateup]
// 50855936          uw_bf  bf16[8*2048*1024]    (33.6 MB)  [dead after gateup]
// 84410368          dw_bf  bf16[8*1024*2048]    (33.6 MB)
// 117964800         act    bf16[16384*2048]     (67.1 MB)
// total need: 185,073,664 B.  All buffers are written before read within
// every call (router/cvt regenerate x_bf and weights each call), so the
// y-overlay is replay-safe.

__device__ __forceinline__ unsigned short f2bf(float f) {
    union { float f; unsigned u; } v; v.f = f;
    unsigned r = v.u + 0x7fffu + ((v.u >> 16) & 1u);   // RNE
    return (unsigned short)(r >> 16);
}

__device__ __forceinline__ void gl2lds16(const void* g, void* l) {
    __builtin_amdgcn_global_load_lds(
        (const __attribute__((address_space(1))) unsigned int*)g,
        (__attribute__((address_space(3))) unsigned int*)l, 16, 0, 0);
}

// ------------- router: logits, top-2, probs; also emits x in bf16 -------------
__global__ __launch_bounds__(256) void k_router(
    const float* __restrict__ x, const float* __restrict__ rw,
    int* __restrict__ topk_idx, float* __restrict__ topk_prob,
    int* __restrict__ counts, unsigned short* __restrict__ x_bf)
{
    int wave = threadIdx.x >> 6;
    int lane = threadIdx.x & 63;
    int t = blockIdx.x * 4 + wave;

    const float4* xr = (const float4*)(x + (size_t)t * DD);
    float4 xv[4];
#pragma unroll
    for (int i = 0; i < 4; i++) xv[i] = xr[lane + 64 * i];

#pragma unroll
    for (int i = 0; i < 4; i++) {
        ushort4 u4 = make_ushort4(f2bf(xv[i].x), f2bf(xv[i].y),
                                  f2bf(xv[i].z), f2bf(xv[i].w));
        *(ushort4*)(x_bf + (size_t)t * DD + (lane + 64 * i) * 4) = u4;
    }

    float acc[NE];
#pragma unroll
    for (int e = 0; e < NE; e++) {
        const float4* wr = (const float4*)(rw + (size_t)e * DD);
        float s = 0.f;
#pragma unroll
        for (int i = 0; i < 4; i++) {
            float4 w = wr[lane + 64 * i];
            s += xv[i].x * w.x + xv[i].y * w.y + xv[i].z * w.z + xv[i].w * w.w;
        }
        acc[e] = s;
    }
#pragma unroll
    for (int e = 0; e < NE; e++) {
        float s = acc[e];
        for (int m = 32; m >= 1; m >>= 1) s += __shfl_xor(s, m);
        acc[e] = s;
    }
    if (lane == 0) {
        int b0 = 0; float l0 = acc[0];
#pragma unroll
        for (int e = 1; e < NE; e++) if (acc[e] > l0) { l0 = acc[e]; b0 = e; }
        int b1 = -1; float l1 = -3.0e38f;
#pragma unroll
        for (int e = 0; e < NE; e++) if (e != b0 && acc[e] > l1) { l1 = acc[e]; b1 = e; }
        float p0 = 1.f / (1.f + __expf(l1 - l0));
        float p1 = 1.f - p0;
        topk_idx[t * 2 + 0] = b0;  topk_idx[t * 2 + 1] = b1;
        topk_prob[t * 2 + 0] = p0; topk_prob[t * 2 + 1] = p1;
        atomicAdd(&counts[b0], 1);
        atomicAdd(&counts[b1], 1);
    }
}

__global__ void k_scan(const int* __restrict__ counts, int* __restrict__ offsets) {
    if (threadIdx.x == 0) {
        int s = 0;
        for (int e = 0; e < NE; e++) { offsets[e] = s; s += counts[e]; }
        offsets[NE] = s;
    }
}

__global__ __launch_bounds__(256) void k_scatter(
    const int* __restrict__ topk_idx,
    const int* __restrict__ offsets, int* __restrict__ cursor,
    int* __restrict__ token_list, int* __restrict__ slot)
{
    int t = blockIdx.x * 256 + threadIdx.x;
#pragma unroll
    for (int k = 0; k < 2; k++) {
        int e = topk_idx[t * 2 + k];
        int pos = atomicAdd(&cursor[e], 1);
        token_list[offsets[e] + pos] = t;
        slot[t * 2 + k] = offsets[e] + pos;
    }
}

// ---------------- merged f32 -> bf16 bulk convert of gw/uw/dw ----------------
__global__ __launch_bounds__(256) void k_cvt_all(
    const float* __restrict__ gw, const float* __restrict__ uw,
    const float* __restrict__ dw,
    unsigned short* __restrict__ gwb, unsigned short* __restrict__ uwb,
    unsigned short* __restrict__ dwb)
{
    constexpr int SEG = NE * HH * DD / 8;   // 2,097,152 chunks of 8
    int i = blockIdx.x * blockDim.x + threadIdx.x;
    int stride = gridDim.x * blockDim.x;
    for (; i < 3 * SEG; i += stride) {
        const float* in; unsigned short* out; int j = i;
        if (j < SEG)            { in = gw; out = gwb; }
        else if (j < 2 * SEG)   { in = uw; out = uwb; j -= SEG; }
        else                    { in = dw; out = dwb; j -= 2 * SEG; }
        const float4* p = (const float4*)(in + (size_t)j * 8);
        float4 a = p[0], b = p[1];
        uint4 v;
        v.x = (unsigned)f2bf(a.x) | ((unsigned)f2bf(a.y) << 16);
        v.y = (unsigned)f2bf(a.z) | ((unsigned)f2bf(a.w) << 16);
        v.z = (unsigned)f2bf(b.x) | ((unsigned)f2bf(b.y) << 16);
        v.w = (unsigned)f2bf(b.z) | ((unsigned)f2bf(b.w) << 16);
        *(uint4*)(out + (size_t)j * 8) = v;
    }
}

// ================ gateup: BM=128, B-rows=256 (g128+u128), BK=64 ================
// Ring-3 LDS, depth-2 prefetch, counted vmcnt(6). Expert-pinned-to-XCD, m-major.
__global__ __launch_bounds__(512) void k_gateup_v3(
    const unsigned short* __restrict__ xb,
    const unsigned short* __restrict__ gwb,
    const unsigned short* __restrict__ uwb,
    const int* __restrict__ offsets,
    const int* __restrict__ token_list,
    unsigned short* __restrict__ act)
{
    extern __shared__ char lds[];   // 3 * 49152: per buf A 16K | B(G+U interleaved) 32K

    const int bid = blockIdx.x;
    const int e   = bid & 7;            // expert == XCD (L2 locality)
    const int r   = bid >> 3;
    const int m   = r >> 4;             // m-major: all 16 n-slices of an m-tile adjacent
    const int n   = r & 15;
    const int off = offsets[e];
    const int n_e = offsets[e + 1] - off;
    const int m0  = m * 128;
    if (m0 >= n_e) return;
    const int n0g = n * 128;            // gate/up col base

    const int tid = threadIdx.x, lane = tid & 63, wid = tid >> 6;
    const int wm = wid >> 2, wn = wid & 3;          // 2m x 4n
    const int l8 = lane >> 3;
    const int colb = ((lane & 7) * 16) ^ (l8 << 4); // pre-swizzled source col byte

    // 48 chunks (1 KB each) per K-tile: A:0..15, B:16..47. This wave stages 6.
    const char* src[6];
    unsigned ldsoff[6];
#pragma unroll
    for (int i = 0; i < 6; i++) {
        int c = wid * 6 + i;
        if (c < 16) {
            int tr = c * 8 + l8;
            int rg = m0 + tr; if (rg > n_e - 1) rg = n_e - 1;
            int tok = token_list[off + rg];
            src[i] = (const char*)xb + (size_t)tok * (DD * 2) + colb;
            ldsoff[i] = c * 1024u;
        } else {
            int cb = c - 16;
            int tr = cb * 8 + l8;
            int wr = tr >> 6, w = tr & 63;
            const unsigned short* W = (w < 32) ? gwb : uwb;
            int wcol = n0g + wr * 32 + (w & 31);
            src[i] = (const char*)W + ((size_t)e * HH + wcol) * (DD * 2) + colb;
            ldsoff[i] = 16384u + cb * 1024u;
        }
    }

    f32x4 acc[4][4] = {};   // [mi][nj]: nj 0,1 = gate, nj 2,3 = up

#define GU_STAGE(T) do { char* b_ = lds + ((T) % 3) * 49152u; \
    _Pragma("unroll") for (int i_ = 0; i_ < 6; i_++) \
        gl2lds16(src[i_] + (T) * 128, b_ + ldsoff[i_]); } while (0)

    GU_STAGE(0);
    GU_STAGE(1);
    asm volatile("s_waitcnt vmcnt(6)" ::: "memory");
    __builtin_amdgcn_s_barrier();
    asm volatile("" ::: "memory");

    constexpr int NT = (DD * 2) / 128;   // 16 K-tiles
    for (int t = 0; t < NT; ++t) {
        if (t + 2 < NT) GU_STAGE(t + 2);
        const char* La = lds + (t % 3) * 49152u;
        const char* Lb = La + 16384;
        __builtin_amdgcn_s_setprio(1);
#pragma unroll
        for (int kk = 0; kk < 2; kk++) {
            const int kb = kk * 64 + (lane >> 4) * 16;
            bf16x8 af[4], bfr[4];
#pragma unroll
            for (int mi = 0; mi < 4; mi++) {
                int row = wm * 64 + mi * 16 + (lane & 15);
                af[mi] = *(const bf16x8*)(La + row * 128 + (kb ^ ((row & 7) << 4)));
            }
#pragma unroll
            for (int nj = 0; nj < 4; nj++) {
                int br = wn * 64 + nj * 16 + (lane & 15);
                bfr[nj] = *(const bf16x8*)(Lb + br * 128 + (kb ^ ((br & 7) << 4)));
            }
#pragma unroll
            for (int mi = 0; mi < 4; mi++)
#pragma unroll
                for (int nj = 0; nj < 4; nj++)
                    acc[mi][nj] = __builtin_amdgcn_mfma_f32_16x16x32_bf16(af[mi], bfr[nj], acc[mi][nj], 0, 0, 0);
        }
        __builtin_amdgcn_s_setprio(0);
        if (t + 2 < NT)      asm volatile("s_waitcnt vmcnt(6)" ::: "memory");
        else if (t + 1 < NT) asm volatile("s_waitcnt vmcnt(0)" ::: "memory");
        __builtin_amdgcn_s_barrier();
        asm volatile("" ::: "memory");
    }
#undef GU_STAGE

    // epilogue: silu(g)*u -> act bf16
#pragma unroll
    for (int mi = 0; mi < 4; mi++) {
#pragma unroll
        for (int r2 = 0; r2 < 4; r2++) {
            int row = wm * 64 + mi * 16 + (lane >> 4) * 4 + r2;
            int rg = m0 + row;
            if (rg >= n_e) continue;
            size_t rowbase = (size_t)(off + rg) * HH + n0g + wn * 32;
#pragma unroll
            for (int nj = 0; nj < 2; nj++) {
                float gg = acc[mi][nj][r2];
                float uu = acc[mi][nj + 2][r2];
                float sv = gg / (1.f + __expf(-gg)) * uu;
                act[rowbase + nj * 16 + (lane & 15)] = f2bf(sv);
            }
        }
    }
}

// ================ down: BM=128, BN=256, BK=64 -> y[slot] f32 (no atomics) ================
__global__ __launch_bounds__(512) void k_down_v3(
    const unsigned short* __restrict__ act,
    const unsigned short* __restrict__ dwb,
    const int* __restrict__ offsets,
    float* __restrict__ y)
{
    extern __shared__ char lds[];   // 3 * 49152: per buf A 16K | B 32K

    const int bid = blockIdx.x;
    const int e   = bid & 7;
    const int r   = bid >> 3;
    const int m   = r >> 2;
    const int n   = r & 3;
    const int off = offsets[e];
    const int n_e = offsets[e + 1] - off;
    const int m0  = m * 128;
    if (m0 >= n_e) return;
    const int n0  = n * 256;              // D col base

    const int tid = threadIdx.x, lane = tid & 63, wid = tid >> 6;
    const int wm = wid >> 2, wn = wid & 3;
    const int l8 = lane >> 3;
    const int colb = ((lane & 7) * 16) ^ (l8 << 4);

    const char* src[6];
    unsigned ldsoff[6];
#pragma unroll
    for (int i = 0; i < 6; i++) {
        int c = wid * 6 + i;
        if (c < 16) {
            int tr = c * 8 + l8;
            int rg = m0 + tr; if (rg > n_e - 1) rg = n_e - 1;
            src[i] = (const char*)act + (size_t)(off + rg) * (HH * 2) + colb;
            ldsoff[i] = c * 1024u;
        } else {
            int cb = c - 16;
            int tr = cb * 8 + l8;
            src[i] = (const char*)dwb + ((size_t)e * DD + n0 + tr) * (HH * 2) + colb;
            ldsoff[i] = 16384u + cb * 1024u;
        }
    }

    f32x4 acc[4][4] = {};

#define DN_STAGE(T) do { char* b_ = lds + ((T) % 3) * 49152u; \
    _Pragma("unroll") for (int i_ = 0; i_ < 6; i_++) \
        gl2lds16(src[i_] + (T) * 128, b_ + ldsoff[i_]); } while (0)

    DN_STAGE(0);
    DN_STAGE(1);
    asm volatile("s_waitcnt vmcnt(6)" ::: "memory");
    __builtin_amdgcn_s_barrier();
    asm volatile("" ::: "memory");

    constexpr int NT = (HH * 2) / 128;   // 32 K-tiles
    for (int t = 0; t < NT; ++t) {
        if (t + 2 < NT) DN_STAGE(t + 2);
        const char* La = lds + (t % 3) * 49152u;
        const char* Lb = La + 16384;
        __builtin_amdgcn_s_setprio(1);
#pragma unroll
        for (int kk = 0; kk < 2; kk++) {
            const int kb = kk * 64 + (lane >> 4) * 16;
            bf16x8 af[4], bfr[4];
#pragma unroll
            for (int mi = 0; mi < 4; mi++) {
                int row = wm * 64 + mi * 16 + (lane & 15);
                af[mi] = *(const bf16x8*)(La + row * 128 + (kb ^ ((row & 7) << 4)));
            }
#pragma unroll
            for (int nj = 0; nj < 4; nj++) {
                int br = wn * 64 + nj * 16 + (lane & 15);
                bfr[nj] = *(const bf16x8*)(Lb + br * 128 + (kb ^ ((br & 7) << 4)));
            }
#pragma unroll
            for (int mi = 0; mi < 4; mi++)
#pragma unroll
                for (int nj = 0; nj < 4; nj++)
                    acc[mi][nj] = __builtin_amdgcn_mfma_f32_16x16x32_bf16(af[mi], bfr[nj], acc[mi][nj], 0, 0, 0);
        }
        __builtin_amdgcn_s_setprio(0);
        if (t + 2 < NT)      asm volatile("s_waitcnt vmcnt(6)" ::: "memory");
        else if (t + 1 < NT) asm volatile("s_waitcnt vmcnt(0)" ::: "memory");
        __builtin_amdgcn_s_barrier();
        asm volatile("" ::: "memory");
    }
#undef DN_STAGE

    // epilogue: y[slot row] = result (f32, non-atomic; combine applies probs)
#pragma unroll
    for (int mi = 0; mi < 4; mi++) {
#pragma unroll
        for (int r2 = 0; r2 < 4; r2++) {
            int row = wm * 64 + mi * 16 + (lane >> 4) * 4 + r2;
            int rg = m0 + row;
            if (rg >= n_e) continue;
            size_t ybase = (size_t)(off + rg) * DD + n0 + wn * 64;
#pragma unroll
            for (int nj = 0; nj < 4; nj++)
                y[ybase + nj * 16 + (lane & 15)] = acc[mi][nj][r2];
        }
    }
}

// ---------------- combine: out[t] = p0*y[slot0] + p1*y[slot1] ----------------
__global__ __launch_bounds__(256) void k_combine(
    const float* __restrict__ y,
    const int* __restrict__ slot,
    const float* __restrict__ topk_prob,
    float* __restrict__ out)
{
    int t = blockIdx.x * 2 + (threadIdx.x >> 7);
    int i = threadIdx.x & 127;            // 8-col chunk index
    int s0 = slot[t * 2 + 0], s1 = slot[t * 2 + 1];
    float p0 = topk_prob[t * 2 + 0], p1 = topk_prob[t * 2 + 1];
    const float4* ya = (const float4*)(y + (size_t)s0 * DD + i * 8);
    const float4* yb = (const float4*)(y + (size_t)s1 * DD + i * 8);
    float4 a0 = ya[0], a1 = ya[1], b0 = yb[0], b1 = yb[1];
    float4 o0, o1;
    o0.x = p0 * a0.x + p1 * b0.x;  o0.y = p0 * a0.y + p1 * b0.y;
    o0.z = p0 * a0.z + p1 * b0.z;  o0.w = p0 * a0.w + p1 * b0.w;
    o1.x = p0 * a1.x + p1 * b1.x;  o1.y = p0 * a1.y + p1 * b1.y;
    o1.z = p0 * a1.z + p1 * b1.z;  o1.w = p0 * a1.w + p1 * b1.w;
    float4* op = (float4*)(out + (size_t)t * DD + i * 8);
    op[0] = o0;
    op[1] = o1;
}

extern "C" void kernel_launch(void* const* d_in, const int* in_sizes, int n_in,
                              void* d_out, int out_size, void* d_ws, size_t ws_size,
                              hipStream_t stream) {
    const float* x  = (const float*)d_in[0];
    const float* rw = (const float*)d_in[1];
    const float* gw = (const float*)d_in[2];
    const float* uw = (const float*)d_in[3];
    const float* dw = (const float*)d_in[4];
    float* out = (float*)d_out;

    char* ws = (char*)d_ws;
    int*   topk_idx   = (int*)(ws + 0);
    float* topk_prob  = (float*)(ws + 65536);
    int*   counts     = (int*)(ws + 131072);
    int*   cursor     = (int*)(ws + 131104);
    int*   offsets    = (int*)(ws + 131136);
    int*   token_list = (int*)(ws + 131264);
    int*   slot       = (int*)(ws + 196800);

    unsigned short* x_bf  = (unsigned short*)(ws + 524288);
    float*          y     = (float*)(ws + 524288);   // overlays x_bf/gw_bf/uw_bf (dead by down)
    unsigned short* gw_bf = (unsigned short*)(ws + 17301504);
    unsigned short* uw_bf = (unsigned short*)(ws + 50855936);
    unsigned short* dw_bf = (unsigned short*)(ws + 84410368);
    unsigned short* act   = (unsigned short*)(ws + 117964800);

    hipMemsetAsync(ws + 131072, 0, 64, stream);   // counts + cursor

    k_router<<<TOK / 4, 256, 0, stream>>>(x, rw, topk_idx, topk_prob, counts, x_bf);
    k_scan<<<1, 64, 0, stream>>>(counts, offsets);
    k_scatter<<<TOK / 256, 256, 0, stream>>>(topk_idx, offsets, cursor,
                                             token_list, slot);

    k_cvt_all<<<2048, 256, 0, stream>>>(gw, uw, dw, gw_bf, uw_bf, dw_bf);

    // gateup: expert e pinned to XCD e; r = m*16 + n (m-major within expert)
    k_gateup_v3<<<16384, 512, 147456, stream>>>(x_bf, gw_bf, uw_bf, offsets,
                                                token_list, act);
    // down: expert e pinned to XCD e; r = m*4 + n; writes y (no atomics)
    k_down_v3<<<4096, 512, 147456, stream>>>(act, dw_bf, offsets, y);

    k_combine<<<TOK / 2, 256, 0, stream>>>(y, slot, topk_prob, out);
}